// Round 2
// baseline (8714.787 us; speedup 1.0000x reference)
//
#include <hip/hip_runtime.h>
#include <math.h>

#define B_ 64
#define T_ 2048
#define E_ 128
#define H_ 128
#define G3_ 384   // 3*H
#define C_ 32
#define M_ (T_ * B_)   // 131072 tokens

// ---------------------------------------------------------------------------
// K1/K3: gi[m][g] = bias[g] + dot(w[g][:], row_m[:]) ; m = t*B + b
// GATHER: row_m = emb[x[b*T+t]] ; else row_m = src[m]
// r=2 weight-stationary: thread g holds w[g] and w[g+192] (256 VGPRs), so
// each LDS b128 broadcast feeds 8 FMAs instead of 4 (LDS-pipe was the limit).
// ---------------------------------------------------------------------------
template <bool GATHER>
__global__ __launch_bounds__(192, 1) void gates_gemm(
    const float* __restrict__ src,   // emb [V,128] or y [M,128]
    const int*   __restrict__ xidx,  // x [B,T] or nullptr
    const float* __restrict__ w,     // [384,128]
    const float* __restrict__ bias,  // [384]
    float* __restrict__ gi)          // [M,384]
{
    const int g = threadIdx.x;  // 0..191
    float4 wr0[32], wr1[32];
    const float4* w40 = (const float4*)(w + g * 128);
    const float4* w41 = (const float4*)(w + (g + 192) * 128);
#pragma unroll
    for (int i = 0; i < 32; i++) { wr0[i] = w40[i]; wr1[i] = w41[i]; }
    const float bg0 = bias[g];
    const float bg1 = bias[g + 192];

    __shared__ __align__(16) float rows[8][128];

    for (int grp = blockIdx.x; grp < M_ / 8; grp += gridDim.x) {
        const int m0 = grp * 8;
        __syncthreads();  // protect rows[] from readers of previous iter
        for (int i = g; i < 8 * 128; i += 192) {
            const int mm = m0 + (i >> 7);
            const int k = i & 127;
            long row;
            if (GATHER) {
                const int t = mm >> 6;      // m = t*B + b, B=64
                const int b = mm & 63;
                row = (long)xidx[b * T_ + t];
            } else {
                row = mm;
            }
            rows[i >> 7][k] = src[row * 128 + k];
        }
        __syncthreads();
#pragma unroll
        for (int s = 0; s < 8; s++) {
            const float4* h4 = (const float4*)rows[s];
            float a00 = bg0, a01 = 0.f, a10 = bg1, a11 = 0.f;
#pragma unroll
            for (int i = 0; i < 32; i += 2) {
                float4 ha = h4[i], hb = h4[i + 1];
                a00 = fmaf(wr0[i].w, ha.w, fmaf(wr0[i].z, ha.z, fmaf(wr0[i].y, ha.y, fmaf(wr0[i].x, ha.x, a00))));
                a10 = fmaf(wr1[i].w, ha.w, fmaf(wr1[i].z, ha.z, fmaf(wr1[i].y, ha.y, fmaf(wr1[i].x, ha.x, a10))));
                a01 = fmaf(wr0[i+1].w, hb.w, fmaf(wr0[i+1].z, hb.z, fmaf(wr0[i+1].y, hb.y, fmaf(wr0[i+1].x, hb.x, a01))));
                a11 = fmaf(wr1[i+1].w, hb.w, fmaf(wr1[i+1].z, hb.z, fmaf(wr1[i+1].y, hb.y, fmaf(wr1[i+1].x, hb.x, a11))));
            }
            gi[(long)(m0 + s) * G3_ + g]       = a00 + a01;
            gi[(long)(m0 + s) * G3_ + g + 192] = a10 + a11;
        }
    }
}

// ---------------------------------------------------------------------------
// K2/K4: GRU recurrence. One block per batch element, 192 threads.
// Thread g owns w_hh rows g and g+192 in registers (256 VGPRs); h broadcast
// via LDS — each b128 h read now feeds 8 FMAs (was 4), halving LDS-pipe load.
// gi layout [t*B+b][384]; y layout [t*B+b][128].
// ---------------------------------------------------------------------------
__global__ __launch_bounds__(192, 1) void gru_layer(
    const float* __restrict__ gi,    // [M,384]
    const float* __restrict__ w_hh,  // [384,128]
    const float* __restrict__ b_hh,  // [384]
    float* __restrict__ y)           // [M,128]
{
    const int g = threadIdx.x;  // 0..191
    const int b = blockIdx.x;

    float4 wr0[32], wr1[32];
    const float4* w40 = (const float4*)(w_hh + g * 128);
    const float4* w41 = (const float4*)(w_hh + (g + 192) * 128);
#pragma unroll
    for (int i = 0; i < 32; i++) { wr0[i] = w40[i]; wr1[i] = w41[i]; }
    const float bg0 = b_hh[g];
    const float bg1 = b_hh[g + 192];

    __shared__ __align__(16) float h_lds[128];
    __shared__ float gh_lds[384];

    float h_own = 0.f;  // valid for g < 128
    if (g < 128) h_lds[g] = 0.f;
    __syncthreads();

    const float* gi_b = gi + (long)b * G3_;
    float* y_b = y + (long)b * H_;

    for (int t = 0; t < T_; t++) {
        const float* gi_t = gi_b + (long)t * (B_ * G3_);
        float ir = 0.f, iz = 0.f, in_ = 0.f;
        if (g < 128) {  // prefetch input gates (hidden behind the dot)
            ir = gi_t[g];
            iz = gi_t[128 + g];
            in_ = gi_t[256 + g];
        }
        // gh_row = b_hh[row] + dot(w_hh[row], h) for row = g and g+192
        const float4* h4 = (const float4*)h_lds;
        float a00 = bg0, a01 = 0.f, a10 = bg1, a11 = 0.f;
#pragma unroll
        for (int i = 0; i < 32; i += 2) {
            float4 ha = h4[i], hb = h4[i + 1];
            a00 = fmaf(wr0[i].w, ha.w, fmaf(wr0[i].z, ha.z, fmaf(wr0[i].y, ha.y, fmaf(wr0[i].x, ha.x, a00))));
            a10 = fmaf(wr1[i].w, ha.w, fmaf(wr1[i].z, ha.z, fmaf(wr1[i].y, ha.y, fmaf(wr1[i].x, ha.x, a10))));
            a01 = fmaf(wr0[i+1].w, hb.w, fmaf(wr0[i+1].z, hb.z, fmaf(wr0[i+1].y, hb.y, fmaf(wr0[i+1].x, hb.x, a01))));
            a11 = fmaf(wr1[i+1].w, hb.w, fmaf(wr1[i+1].z, hb.z, fmaf(wr1[i+1].y, hb.y, fmaf(wr1[i+1].x, hb.x, a11))));
        }
        gh_lds[g]       = a00 + a01;
        gh_lds[g + 192] = a10 + a11;
        __syncthreads();   // gh ready; h_lds reads done
        if (g < 128) {
            const float hr = gh_lds[g];
            const float hz = gh_lds[128 + g];
            const float hn = gh_lds[256 + g];
            const float r = 1.f / (1.f + __expf(-(ir + hr)));
            const float z = 1.f / (1.f + __expf(-(iz + hz)));
            const float narg = in_ + r * hn;
            // tanh(x) = 1 - 2/(exp(2x)+1)
            const float n = 1.f - 2.f / (__expf(2.f * narg) + 1.f);
            h_own = (1.f - z) * n + z * h_own;
            h_lds[g] = h_own;
            y_b[(long)t * (B_ * H_) + g] = h_own;
        }
        __syncthreads();   // h_lds updated for next step
    }
}

// ---------------------------------------------------------------------------
// K5: out[b*T+t][c] = relu(fc_b[c] + dot(fc_w[c], y[t*B+b]))
// 256 threads: thread = slot(0..7) * 32 + c ; 8 tokens per pass.
// ---------------------------------------------------------------------------
__global__ __launch_bounds__(256, 2) void fc_relu(
    const float* __restrict__ y,     // [M,128]
    const float* __restrict__ fc_w,  // [32,128]
    const float* __restrict__ fc_b,  // [32]
    float* __restrict__ out)         // [B*T,32]
{
    const int tid = threadIdx.x;
    const int c = tid & 31;
    const int slot = tid >> 5;

    float4 wr[32];
    const float4* w4 = (const float4*)(fc_w + c * 128);
#pragma unroll
    for (int i = 0; i < 32; i++) wr[i] = w4[i];
    const float bc = fc_b[c];

    __shared__ __align__(16) float rows[8][128];

    for (int grp = blockIdx.x; grp < M_ / 8; grp += gridDim.x) {
        const int m0 = grp * 8;
        __syncthreads();
        for (int i = tid; i < 8 * 128; i += 256) {
            rows[i >> 7][i & 127] = y[(long)m0 * 128 + i];
        }
        __syncthreads();
        const float4* h4 = (const float4*)rows[slot];
        float a0 = bc, a1 = 0.f, a2 = 0.f, a3 = 0.f;
#pragma unroll
        for (int i = 0; i < 32; i += 4) {
            float4 h0 = h4[i], h1 = h4[i + 1], h2 = h4[i + 2], h3 = h4[i + 3];
            a0 = fmaf(wr[i].w, h0.w, fmaf(wr[i].z, h0.z, fmaf(wr[i].y, h0.y, fmaf(wr[i].x, h0.x, a0))));
            a1 = fmaf(wr[i+1].w, h1.w, fmaf(wr[i+1].z, h1.z, fmaf(wr[i+1].y, h1.y, fmaf(wr[i+1].x, h1.x, a1))));
            a2 = fmaf(wr[i+2].w, h2.w, fmaf(wr[i+2].z, h2.z, fmaf(wr[i+2].y, h2.y, fmaf(wr[i+2].x, h2.x, a2))));
            a3 = fmaf(wr[i+3].w, h3.w, fmaf(wr[i+3].z, h3.z, fmaf(wr[i+3].y, h3.y, fmaf(wr[i+3].x, h3.x, a3))));
        }
        float acc = (a0 + a1) + (a2 + a3);
        acc = fmaxf(acc, 0.f);
        const int m = m0 + slot;
        const int t = m >> 6;
        const int b = m & 63;
        out[((long)b * T_ + t) * C_ + c] = acc;
    }
}

// ---------------------------------------------------------------------------
extern "C" void kernel_launch(void* const* d_in, const int* in_sizes, int n_in,
                              void* d_out, int out_size, void* d_ws, size_t ws_size,
                              hipStream_t stream) {
    const int*   x     = (const int*)d_in[0];
    const float* emb   = (const float*)d_in[1];
    const float* w_ih0 = (const float*)d_in[2];
    const float* w_hh0 = (const float*)d_in[3];
    const float* b_ih0 = (const float*)d_in[4];
    const float* b_hh0 = (const float*)d_in[5];
    const float* w_ih1 = (const float*)d_in[6];
    const float* w_hh1 = (const float*)d_in[7];
    const float* b_ih1 = (const float*)d_in[8];
    const float* b_hh1 = (const float*)d_in[9];
    const float* fc_w  = (const float*)d_in[10];
    const float* fc_b  = (const float*)d_in[11];
    float* out = (float*)d_out;

    // workspace: gi [M,384] fp32 (201.3 MB, reused for both layers) + y [M,128] (67.1 MB)
    float* gi = (float*)d_ws;
    float* yb = (float*)((char*)d_ws + (size_t)M_ * G3_ * sizeof(float));

    // layer 0 input gates (embedding gather fused); 256 blocks = 1 fat block/CU
    gates_gemm<true><<<256, 192, 0, stream>>>(emb, x, w_ih0, b_ih0, gi);
    // layer 0 recurrence
    gru_layer<<<B_, 192, 0, stream>>>(gi, w_hh0, b_hh0, yb);
    // layer 1 input gates
    gates_gemm<false><<<256, 192, 0, stream>>>(yb, nullptr, w_ih1, b_ih1, gi);
    // layer 1 recurrence (overwrites yb; gi1 already computed)
    gru_layer<<<B_, 192, 0, stream>>>(gi, w_hh1, b_hh1, yb);
    // FC + ReLU
    fc_relu<<<512, 256, 0, stream>>>(yb, fc_w, fc_b, out);
}

// Round 3
// 3448.590 us; speedup vs baseline: 2.5271x; 2.5271x over previous
//
#include <hip/hip_runtime.h>
#include <math.h>

#define B_ 64
#define T_ 2048
#define E_ 128
#define H_ 128
#define G3_ 384   // 3*H
#define C_ 32
#define M_ (T_ * B_)   // 131072 tokens

typedef _Float16 f16x2 __attribute__((ext_vector_type(2)));

__device__ __forceinline__ f16x2 as_h2(unsigned int u) {
    union { unsigned int u; f16x2 h; } c; c.u = u; return c.h;
}

#if __has_builtin(__builtin_amdgcn_fdot2)
__device__ __forceinline__ float fdot2_acc(f16x2 a, f16x2 b, float c) {
    return __builtin_amdgcn_fdot2(a, b, c, false);
}
#else
__device__ __forceinline__ float fdot2_acc(f16x2 a, f16x2 b, float c) {
    return fmaf((float)a.y, (float)b.y, fmaf((float)a.x, (float)b.x, c));
}
#endif

// ---------------------------------------------------------------------------
// K1/K3: gi[m][g] = bias[g] + dot(w[g][:], row_m[:]) ; m = t*B + b
// GATHER: row_m = emb[x[b*T+t]] ; else row_m = src[m]
// (round-1 version — known good)
// ---------------------------------------------------------------------------
template <bool GATHER>
__global__ __launch_bounds__(384, 2) void gates_gemm(
    const float* __restrict__ src,   // emb [V,128] or y [M,128]
    const int*   __restrict__ xidx,  // x [B,T] or nullptr
    const float* __restrict__ w,     // [384,128]
    const float* __restrict__ bias,  // [384]
    float* __restrict__ gi)          // [M,384]
{
    const int g = threadIdx.x;  // 0..383
    float4 wr[32];
    const float4* w4 = (const float4*)(w + g * 128);
#pragma unroll
    for (int i = 0; i < 32; i++) wr[i] = w4[i];
    const float bg = bias[g];

    __shared__ __align__(16) float rows[8][128];

    for (int grp = blockIdx.x; grp < M_ / 8; grp += gridDim.x) {
        const int m0 = grp * 8;
        __syncthreads();  // protect rows[] from readers of previous iter
        for (int i = g; i < 8 * 128; i += 384) {
            const int mm = m0 + (i >> 7);
            const int k = i & 127;
            long row;
            if (GATHER) {
                const int t = mm >> 6;      // m = t*B + b, B=64
                const int b = mm & 63;
                row = (long)xidx[b * T_ + t];
            } else {
                row = mm;
            }
            rows[i >> 7][k] = src[row * 128 + k];
        }
        __syncthreads();
#pragma unroll
        for (int s = 0; s < 8; s++) {
            const float4* h4 = (const float4*)rows[s];
            float a0 = bg, a1 = 0.f, a2 = 0.f, a3 = 0.f;
#pragma unroll
            for (int i = 0; i < 32; i += 4) {
                float4 h0 = h4[i], h1 = h4[i + 1], h2 = h4[i + 2], h3 = h4[i + 3];
                a0 = fmaf(wr[i].w, h0.w, fmaf(wr[i].z, h0.z, fmaf(wr[i].y, h0.y, fmaf(wr[i].x, h0.x, a0))));
                a1 = fmaf(wr[i+1].w, h1.w, fmaf(wr[i+1].z, h1.z, fmaf(wr[i+1].y, h1.y, fmaf(wr[i+1].x, h1.x, a1))));
                a2 = fmaf(wr[i+2].w, h2.w, fmaf(wr[i+2].z, h2.z, fmaf(wr[i+2].y, h2.y, fmaf(wr[i+2].x, h2.x, a2))));
                a3 = fmaf(wr[i+3].w, h3.w, fmaf(wr[i+3].z, h3.z, fmaf(wr[i+3].y, h3.y, fmaf(wr[i+3].x, h3.x, a3))));
            }
            gi[(long)(m0 + s) * G3_ + g] = (a0 + a1) + (a2 + a3);
        }
    }
}

// ---------------------------------------------------------------------------
// K2/K4: GRU recurrence. One block per batch element, 384 threads.
// f16 everywhere on the dot path: weights converted once to 64 half2 VGPRs
// (half the pressure of fp32 — target: actual residency this time), h
// broadcast f16 through LDS (16 b128/thread/step instead of 32),
// v_dot2_f32_f16 accumulating in fp32. State h, gi, gates stay fp32.
// ---------------------------------------------------------------------------
__global__ __launch_bounds__(384, 1) void gru_layer(
    const float* __restrict__ gi,    // [M,384]
    const float* __restrict__ w_hh,  // [384,128]
    const float* __restrict__ b_hh,  // [384]
    float* __restrict__ y)           // [M,128]
{
    const int g = threadIdx.x;  // 0..383
    const int b = blockIdx.x;

    // one-time load + convert: w_hh row g -> 64 packed half2 registers
    f16x2 wr[64];
    const float4* w4 = (const float4*)(w_hh + g * 128);
#pragma unroll
    for (int i = 0; i < 32; i++) {
        float4 v = w4[i];
        wr[2 * i]     = (f16x2){(_Float16)v.x, (_Float16)v.y};
        wr[2 * i + 1] = (f16x2){(_Float16)v.z, (_Float16)v.w};
    }
    const float bg = b_hh[g];

    __shared__ __align__(16) f16x2 h_lds[64];   // 128 h values, f16
    __shared__ float gh_lds[384];

    float h_own = 0.f;  // fp32 state, valid for g < 128
    if (g < 64) h_lds[g] = (f16x2){(_Float16)0.f, (_Float16)0.f};
    __syncthreads();

    const float* gi_b = gi + (long)b * G3_;
    float* y_b = y + (long)b * H_;

    for (int t = 0; t < T_; t++) {
        const float* gi_t = gi_b + (long)t * (B_ * G3_);
        float ir = 0.f, iz = 0.f, in_ = 0.f;
        if (g < 128) {  // prefetch input gates (hidden behind the dot)
            ir = gi_t[g];
            iz = gi_t[128 + g];
            in_ = gi_t[256 + g];
        }
        // gh_g = b_hh[g] + dot(w_hh[g], h): 16 b128 broadcast reads, 64 dot2
        const uint4* h16 = (const uint4*)h_lds;
        float a0 = bg, a1 = 0.f, a2 = 0.f, a3 = 0.f;
#pragma unroll
        for (int i = 0; i < 16; i++) {
            uint4 u = h16[i];
            a0 = fdot2_acc(wr[4 * i + 0], as_h2(u.x), a0);
            a1 = fdot2_acc(wr[4 * i + 1], as_h2(u.y), a1);
            a2 = fdot2_acc(wr[4 * i + 2], as_h2(u.z), a2);
            a3 = fdot2_acc(wr[4 * i + 3], as_h2(u.w), a3);
        }
        gh_lds[g] = (a0 + a1) + (a2 + a3);
        __syncthreads();   // gh ready; h_lds reads done
        if (g < 128) {
            const float hr = gh_lds[g];
            const float hz = gh_lds[128 + g];
            const float hn = gh_lds[256 + g];
            const float r = 1.f / (1.f + __expf(-(ir + hr)));
            const float z = 1.f / (1.f + __expf(-(iz + hz)));
            const float narg = in_ + r * hn;
            // tanh(x) = 1 - 2/(exp(2x)+1)
            const float n = 1.f - 2.f / (__expf(2.f * narg) + 1.f);
            h_own = (1.f - z) * n + z * h_own;
            ((_Float16*)h_lds)[g] = (_Float16)h_own;   // f16 broadcast copy
            y_b[(long)t * (B_ * H_) + g] = h_own;      // fp32 out
        }
        __syncthreads();   // h_lds updated for next step
    }
}

// ---------------------------------------------------------------------------
// K5: out[b*T+t][c] = relu(fc_b[c] + dot(fc_w[c], y[t*B+b]))
// ---------------------------------------------------------------------------
__global__ __launch_bounds__(256, 2) void fc_relu(
    const float* __restrict__ y,     // [M,128]
    const float* __restrict__ fc_w,  // [32,128]
    const float* __restrict__ fc_b,  // [32]
    float* __restrict__ out)         // [B*T,32]
{
    const int tid = threadIdx.x;
    const int c = tid & 31;
    const int slot = tid >> 5;

    float4 wr[32];
    const float4* w4 = (const float4*)(fc_w + c * 128);
#pragma unroll
    for (int i = 0; i < 32; i++) wr[i] = w4[i];
    const float bc = fc_b[c];

    __shared__ __align__(16) float rows[8][128];

    for (int grp = blockIdx.x; grp < M_ / 8; grp += gridDim.x) {
        const int m0 = grp * 8;
        __syncthreads();
        for (int i = tid; i < 8 * 128; i += 256) {
            rows[i >> 7][i & 127] = y[(long)m0 * 128 + i];
        }
        __syncthreads();
        const float4* h4 = (const float4*)rows[slot];
        float a0 = bc, a1 = 0.f, a2 = 0.f, a3 = 0.f;
#pragma unroll
        for (int i = 0; i < 32; i += 4) {
            float4 h0 = h4[i], h1 = h4[i + 1], h2 = h4[i + 2], h3 = h4[i + 3];
            a0 = fmaf(wr[i].w, h0.w, fmaf(wr[i].z, h0.z, fmaf(wr[i].y, h0.y, fmaf(wr[i].x, h0.x, a0))));
            a1 = fmaf(wr[i+1].w, h1.w, fmaf(wr[i+1].z, h1.z, fmaf(wr[i+1].y, h1.y, fmaf(wr[i+1].x, h1.x, a1))));
            a2 = fmaf(wr[i+2].w, h2.w, fmaf(wr[i+2].z, h2.z, fmaf(wr[i+2].y, h2.y, fmaf(wr[i+2].x, h2.x, a2))));
            a3 = fmaf(wr[i+3].w, h3.w, fmaf(wr[i+3].z, h3.z, fmaf(wr[i+3].y, h3.y, fmaf(wr[i+3].x, h3.x, a3))));
        }
        float acc = (a0 + a1) + (a2 + a3);
        acc = fmaxf(acc, 0.f);
        const int m = m0 + slot;
        const int t = m >> 6;
        const int b = m & 63;
        out[((long)b * T_ + t) * C_ + c] = acc;
    }
}

// ---------------------------------------------------------------------------
extern "C" void kernel_launch(void* const* d_in, const int* in_sizes, int n_in,
                              void* d_out, int out_size, void* d_ws, size_t ws_size,
                              hipStream_t stream) {
    const int*   x     = (const int*)d_in[0];
    const float* emb   = (const float*)d_in[1];
    const float* w_ih0 = (const float*)d_in[2];
    const float* w_hh0 = (const float*)d_in[3];
    const float* b_ih0 = (const float*)d_in[4];
    const float* b_hh0 = (const float*)d_in[5];
    const float* w_ih1 = (const float*)d_in[6];
    const float* w_hh1 = (const float*)d_in[7];
    const float* b_ih1 = (const float*)d_in[8];
    const float* b_hh1 = (const float*)d_in[9];
    const float* fc_w  = (const float*)d_in[10];
    const float* fc_b  = (const float*)d_in[11];
    float* out = (float*)d_out;

    // workspace: gi [M,384] fp32 (201.3 MB, reused for both layers) + y [M,128] (67.1 MB)
    float* gi = (float*)d_ws;
    float* yb = (float*)((char*)d_ws + (size_t)M_ * G3_ * sizeof(float));

    // layer 0 input gates (embedding gather fused)
    gates_gemm<true><<<512, 384, 0, stream>>>(emb, x, w_ih0, b_ih0, gi);
    // layer 0 recurrence
    gru_layer<<<B_, 384, 0, stream>>>(gi, w_hh0, b_hh0, yb);
    // layer 1 input gates
    gates_gemm<false><<<512, 384, 0, stream>>>(yb, nullptr, w_ih1, b_ih1, gi);
    // layer 1 recurrence (overwrites yb; gi1 already computed)
    gru_layer<<<B_, 384, 0, stream>>>(gi, w_hh1, b_hh1, yb);
    // FC + ReLU
    fc_relu<<<512, 256, 0, stream>>>(yb, fc_w, fc_b, out);
}

// Round 4
// 3088.658 us; speedup vs baseline: 2.8215x; 1.1165x over previous
//
#include <hip/hip_runtime.h>
#include <math.h>

#define B_ 64
#define T_ 2048
#define E_ 128
#define H_ 128
#define G3_ 384   // 3*H
#define C_ 32
#define M_ (T_ * B_)   // 131072 tokens

typedef _Float16 f16x2 __attribute__((ext_vector_type(2)));

__device__ __forceinline__ f16x2 as_h2(unsigned int u) {
    union { unsigned int u; f16x2 h; } c; c.u = u; return c.h;
}

#if __has_builtin(__builtin_amdgcn_fdot2)
__device__ __forceinline__ float fdot2_acc(f16x2 a, f16x2 b, float c) {
    return __builtin_amdgcn_fdot2(a, b, c, false);
}
#else
__device__ __forceinline__ float fdot2_acc(f16x2 a, f16x2 b, float c) {
    return fmaf((float)a.y, (float)b.y, fmaf((float)a.x, (float)b.x, c));
}
#endif

// ---------------------------------------------------------------------------
// K1/K3: gi[m][g] = bias[g] + dot(w[g][:], row_m[:]) ; m = t*B + b
// GATHER: row_m = emb[x[b*T+t]] ; else row_m = src[m]
// r=3 f16 weight-stationary: thread g holds w rows {g, g+128, g+256} as
// 192 f16x2 VGPRs; activation rows staged f16 in LDS; each b128 broadcast
// feeds 12 dot2 (1:1.5 LDS:VALU issue — balanced pipes).
// ---------------------------------------------------------------------------
template <bool GATHER>
__global__ __launch_bounds__(128, 1) void gates_gemm(
    const float* __restrict__ src,   // emb [V,128] or y [M,128]
    const int*   __restrict__ xidx,  // x [B,T] or nullptr
    const float* __restrict__ w,     // [384,128]
    const float* __restrict__ bias,  // [384]
    float* __restrict__ gi)          // [M,384]
{
    const int g = threadIdx.x;  // 0..127
    f16x2 wr[3][64];
#pragma unroll
    for (int r = 0; r < 3; r++) {
        const float2* w2 = (const float2*)(w + (g + 128 * r) * 128);
#pragma unroll
        for (int i = 0; i < 64; i++) {
            float2 v = w2[i];
            wr[r][i] = (f16x2){(_Float16)v.x, (_Float16)v.y};
        }
    }
    const float bg0 = bias[g], bg1 = bias[g + 128], bg2 = bias[g + 256];

    __shared__ __align__(16) f16x2 rows[8][64];   // 8 tokens x 128 f16

    for (int grp = blockIdx.x; grp < M_ / 8; grp += gridDim.x) {
        const int m0 = grp * 8;
        __syncthreads();  // protect rows[] from readers of previous iter
        // stage 8 token-rows as f16: thread handles slots j = g + 128k
#pragma unroll
        for (int k = 0; k < 4; k++) {
            const int j = g + 128 * k;          // 0..511 (f16x2 slots)
            const int s = j >> 6;               // token in group
            const int p = j & 63;               // f16x2 pair within row
            const int mm = m0 + s;
            long row;
            if (GATHER) {
                const int t = mm >> 6;          // m = t*B + b, B=64
                const int b = mm & 63;
                row = (long)xidx[b * T_ + t];
            } else {
                row = mm;
            }
            float2 v = ((const float2*)(src + row * 128))[p];
            rows[s][p] = (f16x2){(_Float16)v.x, (_Float16)v.y};
        }
        __syncthreads();
        for (int s = 0; s < 8; s++) {
            const uint4* h16 = (const uint4*)rows[s];
            float a00 = bg0, a01 = 0.f, a10 = bg1, a11 = 0.f, a20 = bg2, a21 = 0.f;
#pragma unroll
            for (int i = 0; i < 16; i++) {
                uint4 u = h16[i];
                f16x2 ux = as_h2(u.x), uy = as_h2(u.y), uz = as_h2(u.z), uw = as_h2(u.w);
                a00 = fdot2_acc(wr[0][4*i+0], ux, a00);
                a10 = fdot2_acc(wr[1][4*i+0], ux, a10);
                a20 = fdot2_acc(wr[2][4*i+0], ux, a20);
                a01 = fdot2_acc(wr[0][4*i+1], uy, a01);
                a11 = fdot2_acc(wr[1][4*i+1], uy, a11);
                a21 = fdot2_acc(wr[2][4*i+1], uy, a21);
                a00 = fdot2_acc(wr[0][4*i+2], uz, a00);
                a10 = fdot2_acc(wr[1][4*i+2], uz, a10);
                a20 = fdot2_acc(wr[2][4*i+2], uz, a20);
                a01 = fdot2_acc(wr[0][4*i+3], uw, a01);
                a11 = fdot2_acc(wr[1][4*i+3], uw, a11);
                a21 = fdot2_acc(wr[2][4*i+3], uw, a21);
            }
            float* go = gi + (long)(m0 + s) * G3_ + g;
            go[0]   = a00 + a01;
            go[128] = a10 + a11;
            go[256] = a20 + a21;
        }
    }
}

// ---------------------------------------------------------------------------
// K2/K4: GRU recurrence. One block per batch element, 128 threads (2 waves).
// Thread g owns w_hh rows {g, g+128, g+256} (192 f16x2 VGPRs) — exactly the
// (r,z,n) triplet for h-dim g, so gate math is fully in-thread: NO gh_lds
// exchange. h broadcast f16 via double-buffered LDS -> ONE barrier per step.
// LDS pipe: 32 b128/step; VALU: 192 dot2/wave/step — balanced.
// ---------------------------------------------------------------------------
__global__ __launch_bounds__(128, 1) void gru_layer(
    const float* __restrict__ gi,    // [M,384]
    const float* __restrict__ w_hh,  // [384,128]
    const float* __restrict__ b_hh,  // [384]
    float* __restrict__ y)           // [M,128]
{
    const int g = threadIdx.x;  // h-dim 0..127
    const int b = blockIdx.x;

    f16x2 wr[3][64];
#pragma unroll
    for (int r = 0; r < 3; r++) {
        const float2* w2 = (const float2*)(w_hh + (g + 128 * r) * 128);
#pragma unroll
        for (int i = 0; i < 64; i++) {
            float2 v = w2[i];
            wr[r][i] = (f16x2){(_Float16)v.x, (_Float16)v.y};
        }
    }
    const float bg0 = b_hh[g], bg1 = b_hh[g + 128], bg2 = b_hh[g + 256];

    __shared__ __align__(16) f16x2 hb[2][64];   // double-buffered h (f16)

    float h_own = 0.f;
    if (g < 64) hb[0][g] = (f16x2){(_Float16)0.f, (_Float16)0.f};
    __syncthreads();

    const float* gi_b = gi + (long)b * G3_;
    float* y_b = y + (long)b * H_;

    for (int t = 0; t < T_; t++) {
        const float* gi_t = gi_b + (long)t * (B_ * G3_);
        // issue gi loads early; consumed after the dot (latency hidden)
        const float ir = gi_t[g];
        const float iz = gi_t[128 + g];
        const float inn = gi_t[256 + g];

        const uint4* h16 = (const uint4*)hb[t & 1];
        float a00 = bg0, a01 = 0.f, a10 = bg1, a11 = 0.f, a20 = bg2, a21 = 0.f;
#pragma unroll
        for (int i = 0; i < 16; i++) {
            uint4 u = h16[i];
            f16x2 ux = as_h2(u.x), uy = as_h2(u.y), uz = as_h2(u.z), uw = as_h2(u.w);
            a00 = fdot2_acc(wr[0][4*i+0], ux, a00);
            a10 = fdot2_acc(wr[1][4*i+0], ux, a10);
            a20 = fdot2_acc(wr[2][4*i+0], ux, a20);
            a01 = fdot2_acc(wr[0][4*i+1], uy, a01);
            a11 = fdot2_acc(wr[1][4*i+1], uy, a11);
            a21 = fdot2_acc(wr[2][4*i+1], uy, a21);
            a00 = fdot2_acc(wr[0][4*i+2], uz, a00);
            a10 = fdot2_acc(wr[1][4*i+2], uz, a10);
            a20 = fdot2_acc(wr[2][4*i+2], uz, a20);
            a01 = fdot2_acc(wr[0][4*i+3], uw, a01);
            a11 = fdot2_acc(wr[1][4*i+3], uw, a11);
            a21 = fdot2_acc(wr[2][4*i+3], uw, a21);
        }
        const float hr = a00 + a01;
        const float hz = a10 + a11;
        const float hn = a20 + a21;

        const float r = 1.f / (1.f + __expf(-(ir + hr)));
        const float z = 1.f / (1.f + __expf(-(iz + hz)));
        const float narg = inn + r * hn;
        const float n = 1.f - 2.f / (__expf(2.f * narg) + 1.f);  // tanh
        h_own = (1.f - z) * n + z * h_own;

        ((_Float16*)hb[(t + 1) & 1])[g] = (_Float16)h_own;  // write OTHER buffer
        y_b[(long)t * (B_ * H_) + g] = h_own;
        __syncthreads();   // single barrier: writes visible before next reads
    }
}

// ---------------------------------------------------------------------------
// K5: out[b*T+t][c] = relu(fc_b[c] + dot(fc_w[c], y[t*B+b]))
// ---------------------------------------------------------------------------
__global__ __launch_bounds__(256, 2) void fc_relu(
    const float* __restrict__ y,     // [M,128]
    const float* __restrict__ fc_w,  // [32,128]
    const float* __restrict__ fc_b,  // [32]
    float* __restrict__ out)         // [B*T,32]
{
    const int tid = threadIdx.x;
    const int c = tid & 31;
    const int slot = tid >> 5;

    float4 wr[32];
    const float4* w4 = (const float4*)(fc_w + c * 128);
#pragma unroll
    for (int i = 0; i < 32; i++) wr[i] = w4[i];
    const float bc = fc_b[c];

    __shared__ __align__(16) float rows[8][128];

    for (int grp = blockIdx.x; grp < M_ / 8; grp += gridDim.x) {
        const int m0 = grp * 8;
        __syncthreads();
        for (int i = tid; i < 8 * 128; i += 256) {
            rows[i >> 7][i & 127] = y[(long)m0 * 128 + i];
        }
        __syncthreads();
        const float4* h4 = (const float4*)rows[slot];
        float a0 = bc, a1 = 0.f, a2 = 0.f, a3 = 0.f;
#pragma unroll
        for (int i = 0; i < 32; i += 4) {
            float4 h0 = h4[i], h1 = h4[i + 1], h2 = h4[i + 2], h3 = h4[i + 3];
            a0 = fmaf(wr[i].w, h0.w, fmaf(wr[i].z, h0.z, fmaf(wr[i].y, h0.y, fmaf(wr[i].x, h0.x, a0))));
            a1 = fmaf(wr[i+1].w, h1.w, fmaf(wr[i+1].z, h1.z, fmaf(wr[i+1].y, h1.y, fmaf(wr[i+1].x, h1.x, a1))));
            a2 = fmaf(wr[i+2].w, h2.w, fmaf(wr[i+2].z, h2.z, fmaf(wr[i+2].y, h2.y, fmaf(wr[i+2].x, h2.x, a2))));
            a3 = fmaf(wr[i+3].w, h3.w, fmaf(wr[i+3].z, h3.z, fmaf(wr[i+3].y, h3.y, fmaf(wr[i+3].x, h3.x, a3))));
        }
        float acc = (a0 + a1) + (a2 + a3);
        acc = fmaxf(acc, 0.f);
        const int m = m0 + slot;
        const int t = m >> 6;
        const int b = m & 63;
        out[((long)b * T_ + t) * C_ + c] = acc;
    }
}

// ---------------------------------------------------------------------------
extern "C" void kernel_launch(void* const* d_in, const int* in_sizes, int n_in,
                              void* d_out, int out_size, void* d_ws, size_t ws_size,
                              hipStream_t stream) {
    const int*   x     = (const int*)d_in[0];
    const float* emb   = (const float*)d_in[1];
    const float* w_ih0 = (const float*)d_in[2];
    const float* w_hh0 = (const float*)d_in[3];
    const float* b_ih0 = (const float*)d_in[4];
    const float* b_hh0 = (const float*)d_in[5];
    const float* w_ih1 = (const float*)d_in[6];
    const float* w_hh1 = (const float*)d_in[7];
    const float* b_ih1 = (const float*)d_in[8];
    const float* b_hh1 = (const float*)d_in[9];
    const float* fc_w  = (const float*)d_in[10];
    const float* fc_b  = (const float*)d_in[11];
    float* out = (float*)d_out;

    // workspace: gi [M,384] fp32 (201.3 MB, reused for both layers) + y [M,128] (67.1 MB)
    float* gi = (float*)d_ws;
    float* yb = (float*)((char*)d_ws + (size_t)M_ * G3_ * sizeof(float));

    // layer 0 input gates (embedding gather fused); 512 blocks = 2/CU, 1 wave/SIMD
    gates_gemm<true><<<512, 128, 0, stream>>>(emb, x, w_ih0, b_ih0, gi);
    // layer 0 recurrence
    gru_layer<<<B_, 128, 0, stream>>>(gi, w_hh0, b_hh0, yb);
    // layer 1 input gates
    gates_gemm<false><<<512, 128, 0, stream>>>(yb, nullptr, w_ih1, b_ih1, gi);
    // layer 1 recurrence (overwrites yb; gi1 already computed)
    gru_layer<<<B_, 128, 0, stream>>>(gi, w_hh1, b_hh1, yb);
    // FC + ReLU
    fc_relu<<<512, 256, 0, stream>>>(yb, fc_w, fc_b, out);
}